// Round 1
// baseline (4705.678 us; speedup 1.0000x reference)
//
#include <hip/hip_runtime.h>
#include <cmath>

// DsoController: autoregressive LSTM + linear_out + Gumbel-max sampling.
// B=16384, T=64, D_IN=128, H=32 (4H=128 gates), C=64.
//
// Strategy: full fp64 compute so actions match a float64 numpy reference
// exactly (argmax over logits+gumbel is brittle at fp32 precision).
// Outputs (actions as float, logits) stored as fp32.
//
// Layout: 256 blocks x 512 threads. Block handles 64 batch rows for all T.
//   lane (tid&63)  = batch row within block
//   gidx (tid>>6)  = wave id 0..7; thread owns cells u in [gidx*4, gidx*4+4)
//     -> computes gate rows {u, 32+u, 64+u, 96+u} (torch order i,f,g,o),
//        keeps cx in registers, publishes hx via LDS each step.
// Weights pre-converted to fp64 into d_ws by prep_kernel (wave-uniform
// scalar loads feed v_fma_f64 without per-use cvt).

#define B_   16384
#define T_   64
#define DIN_ 128
#define H_   32
#define C_   64
#define BB_  64
#define NTH_ 512

// ws layout in doubles:
//   Wih_d  [128*128] @ 0
//   Whh_d  [128* 32] @ 16384
//   Wout_d [ 64* 32] @ 20480
//   bsum_d [128]     @ 22528   (b_ih + b_hh)
//   bout_d [ 64]     @ 22656
//   total 22720 doubles = 181760 bytes

__global__ void prep_kernel(const float* __restrict__ Wih, const float* __restrict__ Whh,
                            const float* __restrict__ Wout,
                            const float* __restrict__ bih, const float* __restrict__ bhh,
                            const float* __restrict__ bout,
                            double* __restrict__ ws) {
  int i = blockIdx.x * blockDim.x + threadIdx.x;
  if (i < 16384) {
    ws[i] = (double)Wih[i];
  } else if (i < 20480) {
    ws[i] = (double)Whh[i - 16384];
  } else if (i < 22528) {
    ws[i] = (double)Wout[i - 20480];
  } else if (i < 22656) {
    ws[i] = (double)bih[i - 22528] + (double)bhh[i - 22528];
  } else if (i < 22720) {
    ws[i] = (double)bout[i - 22656];
  }
}

__device__ __forceinline__ double sigmoid_d(double x) {
  return 1.0 / (1.0 + exp(-x));
}

__global__ __launch_bounds__(NTH_, 2)
void lstm_kernel(const float* __restrict__ x_g, const float* __restrict__ pr_g,
                 const float* __restrict__ nz_g, const double* __restrict__ wsd,
                 float* __restrict__ out) {
  __shared__ float  x_s[BB_][DIN_ + 1];   // +1 pad: stride 129 -> conflict-free
  __shared__ double hx_t[H_][BB_];        // transposed: [k][b]
  __shared__ double redv[8][BB_];
  __shared__ int    redi[8][BB_];

  const int tid  = threadIdx.x;
  const int lane = tid & 63;                                        // batch row in block
  const int gidx = __builtin_amdgcn_readfirstlane(tid >> 6);        // wave id, SGPR
  const int bbase = blockIdx.x * BB_;
  const int b = bbase + lane;

  const double* Wih_d  = wsd;
  const double* Whh_d  = wsd + 16384;
  const double* Wout_d = wsd + 20480;
  const double* bsum_d = wsd + 22528;
  const double* bout_d = wsd + 22656;

  double hxv[H_];
  double cx[4];
#pragma unroll
  for (int k = 0; k < H_; ++k) hxv[k] = 0.0;
  cx[0] = cx[1] = cx[2] = cx[3] = 0.0;

  const long long BT = (long long)B_ * T_;

  for (int t = 0; t < T_; ++t) {
    __syncthreads();  // protect x_s / red arrays reuse across steps
    // ---- stage x tile: 64 rows x 128 floats, 2048 float4s, 4 per thread ----
#pragma unroll
    for (int r = 0; r < 4; ++r) {
      const int p  = tid + r * NTH_;       // float4 id 0..2047
      const int bl = p >> 5;               // row 0..63
      const int k4 = (p & 31) << 2;        // col 0,4,...,124
      const float4 v = *(const float4*)(x_g + (((long long)(bbase + bl)) * T_ + t) * DIN_ + k4);
      x_s[bl][k4 + 0] = v.x; x_s[bl][k4 + 1] = v.y;
      x_s[bl][k4 + 2] = v.z; x_s[bl][k4 + 3] = v.w;
    }
    __syncthreads();

    // ---- gates: acc[g], g = ty*4+cell, row = ty*32 + gidx*4 + cell ----
    double acc[16];
#pragma unroll
    for (int g = 0; g < 16; ++g) {
      const int cell = g & 3, ty = g >> 2;
      const int row = ty * H_ + gidx * 4 + cell;
      double a = bsum_d[row];
      const double* wr = Whh_d + row * H_;
#pragma unroll
      for (int k = 0; k < H_; ++k) a += hxv[k] * wr[k];
      acc[g] = a;
    }
#pragma unroll
    for (int kc = 0; kc < 8; ++kc) {
      double xv[16];
#pragma unroll
      for (int k = 0; k < 16; ++k) xv[k] = (double)x_s[lane][kc * 16 + k];
#pragma unroll
      for (int g = 0; g < 16; ++g) {
        const int cell = g & 3, ty = g >> 2;
        const int row = ty * H_ + gidx * 4 + cell;
        const double* wr = Wih_d + row * DIN_ + kc * 16;
        double a = acc[g];
#pragma unroll
        for (int k = 0; k < 16; ++k) a += xv[k] * wr[k];
        acc[g] = a;
      }
    }

    // ---- cell update: cx in regs, hx -> LDS ----
#pragma unroll
    for (int cell = 0; cell < 4; ++cell) {
      const double i_ = sigmoid_d(acc[cell]);
      const double f_ = sigmoid_d(acc[4 + cell]);
      const double g_ = tanh(acc[8 + cell]);
      const double o_ = sigmoid_d(acc[12 + cell]);
      const double c_ = f_ * cx[cell] + i_ * g_;
      cx[cell] = c_;
      hx_t[gidx * 4 + cell][lane] = o_ * tanh(c_);
    }
    __syncthreads();
#pragma unroll
    for (int k = 0; k < H_; ++k) hxv[k] = hx_t[k][lane];  // also next step's hx

    // ---- logits + gumbel argmax: thread covers c in [gidx*8, gidx*8+8) ----
    const int cbase = gidx * 8;
    const long long pbase = ((long long)b * T_ + t) * C_ + cbase;
    const float4 pv0 = *(const float4*)(pr_g + pbase);
    const float4 pv1 = *(const float4*)(pr_g + pbase + 4);
    const float4 nv0 = *(const float4*)(nz_g + pbase);
    const float4 nv1 = *(const float4*)(nz_g + pbase + 4);
    const float pr8[8] = {pv0.x, pv0.y, pv0.z, pv0.w, pv1.x, pv1.y, pv1.z, pv1.w};
    const float nz8[8] = {nv0.x, nv0.y, nv0.z, nv0.w, nv1.x, nv1.y, nv1.z, nv1.w};

    double best = -1.0e300;
    int bidx = cbase;
    float lbuf[8];
#pragma unroll
    for (int c = 0; c < 8; ++c) {
      const int row = cbase + c;
      double a = bout_d[row] + (double)pr8[c];
      const double* wr = Wout_d + row * H_;
#pragma unroll
      for (int k = 0; k < H_; ++k) a += hxv[k] * wr[k];
      lbuf[c] = (float)a;
      const double gum = -log(-log((double)nz8[c]));
      const double s = a + gum;
      if (s > best) { best = s; bidx = row; }   // strict > : first-max semantics
    }
    *(float4*)(out + BT + pbase)     = make_float4(lbuf[0], lbuf[1], lbuf[2], lbuf[3]);
    *(float4*)(out + BT + pbase + 4) = make_float4(lbuf[4], lbuf[5], lbuf[6], lbuf[7]);

    redv[gidx][lane] = best;
    redi[gidx][lane] = bidx;
    __syncthreads();
    if (gidx == 0) {
      double bv = redv[0][lane];
      int bi = redi[0][lane];
#pragma unroll
      for (int w = 1; w < 8; ++w) {
        const double v = redv[w][lane];
        if (v > bv) { bv = v; bi = redi[w][lane]; }  // strict > : lower c-range wins ties
      }
      out[(long long)b * T_ + t] = (float)bi;
    }
  }
}

extern "C" void kernel_launch(void* const* d_in, const int* in_sizes, int n_in,
                              void* d_out, int out_size, void* d_ws, size_t ws_size,
                              hipStream_t stream) {
  const float* inputs = (const float*)d_in[0];
  const float* priors = (const float*)d_in[1];
  const float* noise  = (const float*)d_in[2];
  const float* W_ih   = (const float*)d_in[3];
  const float* W_hh   = (const float*)d_in[4];
  const float* b_ih   = (const float*)d_in[5];
  const float* b_hh   = (const float*)d_in[6];
  const float* W_out  = (const float*)d_in[7];
  const float* b_out  = (const float*)d_in[8];
  float* out = (float*)d_out;
  double* wsd = (double*)d_ws;

  prep_kernel<<<dim3((22720 + 255) / 256), dim3(256), 0, stream>>>(
      W_ih, W_hh, W_out, b_ih, b_hh, b_out, wsd);

  lstm_kernel<<<dim3(B_ / BB_), dim3(NTH_), 0, stream>>>(
      inputs, priors, noise, wsd, out);
}